// Round 8
// baseline (1754.414 us; speedup 1.0000x reference)
//
#include <hip/hip_runtime.h>
#include <hip/hip_bf16.h>

#define BATCH 8
#define TSEQ 8
#define HH 64
#define WW 64
#define HID 64
#define PT 10   // T + NUM_NODE - 1

typedef __bf16 bf16_t;
typedef __bf16 bf16x8 __attribute__((ext_vector_type(8)));
typedef float  f32x16 __attribute__((ext_vector_type(16)));

// fast transcendentals (v_exp_f32 + v_rcp_f32)
__device__ __forceinline__ float fsigmoid(float v) {
    float e = __builtin_amdgcn_exp2f(-1.4426950408889634f * v);
    return __builtin_amdgcn_rcpf(1.0f + e);
}
__device__ __forceinline__ float ftanh(float v) {
    float e = __builtin_amdgcn_exp2f(2.8853900817779268f * v);   // e^(2v)
    return 1.0f - 2.0f * __builtin_amdgcn_rcpf(1.0f + e);
}

// ---------------------------------------------------------------------------
// Weight pack for 32x32x16 MFMA B-fragments, PHASED chunk order:
// chunks with ci16 < s16 (phase A) first (tap-major), then ci16 >= s16.
//   dst[((chunk*NT32 + nt)*64 + lane)*8 + j]
//     = w[co = nt*32 + (lane&31)][ci = ci16*16 + (lane>>5)*8 + j][tap]
// ---------------------------------------------------------------------------
struct PackSeg { const float* src; bf16_t* dst; int NT32; int KC; int CinReal; int s16; int begin; };
struct PackArgs { PackSeg s[12]; int total; };

__global__ void wpack_all(PackArgs P) {
    int idx = blockIdx.x * 256 + threadIdx.x;
    if (idx >= P.total) return;
    int si = 0;
#pragma unroll
    for (int i = 1; i < 12; ++i) if (idx >= P.s[i].begin) si = i;
    PackSeg sg = P.s[si];
    int l = idx - sg.begin;
    int j    = l & 7;
    int lane = (l >> 3) & 63;
    int rest = l >> 9;
    int nt    = rest % sg.NT32;
    int chunk = rest / sg.NT32;
    int a = 9 * sg.s16;
    int tap, ci16;
    if (chunk < a) { tap = chunk / sg.s16; ci16 = chunk % sg.s16; }
    else {
        int c2 = chunk - a, kb = sg.KC - sg.s16;
        tap = c2 / kb; ci16 = sg.s16 + c2 % kb;
    }
    int co = nt * 32 + (lane & 31);
    int ci = ci16 * 16 + (lane >> 5) * 8 + j;
    float v = (ci < sg.CinReal) ? sg.src[((long)co * sg.CinReal + ci) * 9 + tap] : 0.0f;
    sg.dst[l] = (bf16_t)v;
}

// x (B,T,3,H,W) fp32 -> xb [t][b][y][x][64] bf16 (channels 3..63 zero)
__global__ void xcvt_k(const float* __restrict__ x, bf16_t* __restrict__ xb) {
    int idx = blockIdx.x * 256 + threadIdx.x;
    if (idx >= 8 * 8 * 64 * 64 * 64) return;
    int c  = idx & 63;
    int xx = (idx >> 6) & 63;
    int y  = (idx >> 12) & 63;
    int b  = (idx >> 18) & 7;
    int t  = idx >> 21;
    float v = 0.0f;
    if (c < 3) v = x[((((long)b * TSEQ + t) * 3 + c) * 64 + y) * 64 + xx];
    xb[idx] = (bf16_t)v;
}

// h fp32 NHWC -> NCHW fp32 out
__global__ void hout_k(const float* __restrict__ hf, float* __restrict__ out) {
    int idx = blockIdx.x * 256 + threadIdx.x;
    if (idx >= 8 * 64 * 64 * 64) return;
    int xx = idx & 63;
    int y  = (idx >> 6) & 63;
    int c  = (idx >> 12) & 63;
    int b  = idx >> 18;
    out[idx] = hf[((((long)b * 64 + y) * 64 + xx) * 64) + c];
}

// ---------------------------------------------------------------------------
// Staging helper: SROWS x 66 px x CH channels into padded LDS (PSB = CH*2+8).
// ---------------------------------------------------------------------------
template <int CH, int SROWS, int NTHR>
__device__ __forceinline__ void stage_ph(const bf16_t* __restrict__ src, char* smem,
                                         int b, int y0, int tid) {
    constexpr int NCHP = CH / 8;
    constexpr int PSB  = CH * 2 + 8;
    for (int c = tid; c < SROWS * 66 * NCHP; c += NTHR) {
        int ry = c / (66 * NCHP);
        int r  = c - ry * 66 * NCHP;
        int px = r / NCHP;
        int c2 = r - px * NCHP;
        int gy = y0 + ry - 1, gx = px - 1;
        bf16x8 v = {};
        if ((unsigned)gy < 64u && (unsigned)gx < 64u)
            v = *(const bf16x8*)(src + (((long)b * 64 + gy) * 64 + gx) * CH + c2 * 8);
        *(bf16x8*)(smem + (ry * 66 + px) * PSB + c2 * 16) = v;
    }
}

// ---------------------------------------------------------------------------
// MFMA 32x32x16 implicit-GEMM 3x3 conv with PHASED K-staging:
// phase A stages CIN0 channels (A0), runs 9*CIN0/16 chunks; then the SAME
// LDS buffer is restaged with CIN1 channels (A1) for the remaining chunks.
// Max LDS = one phase => 3x smaller than joint staging => more blocks/CU.
// Waves: wn = w % NW_N owns a 32-wide co tile; wm sweeps MT_W m-tiles.
// blockIdx.x: b = &7 (XCD-pinned), ychunk = >>3. blockIdx.y: node.
// MODE 0: plain conv, out bf16 NHWC.
// MODE 1: gates (COUT=128): sigmoid; co<64 -> rh bf16 (= r*Hb), co>=64 -> z f32.
// MODE 2: cand (COUT=64): h_new = z*h + (1-z)*tanh; writes h fp32 + h bf16.
// ---------------------------------------------------------------------------
struct NP {
    const bf16_t* A0;
    const bf16_t* A1;
    const float*  Zf;
    const float*  Hf;
    const bf16_t* Hb;
    const bf16_t* Wp;
    const float*  bias;
    bf16_t* outB;
    float*  outF;
};
struct NPs { NP n[3]; };

template <int CIN0, int CIN1, int COUT, int MODE, int WAVES, int ROWS, int MINW, int PF>
__global__ __launch_bounds__(WAVES * 64, MINW) void mconv(NPs P)
{
    constexpr int NT32  = COUT / 32;
    constexpr int S16A  = CIN0 / 16;
    constexpr int S16B  = CIN1 / 16;
    constexpr int CHA   = 9 * S16A;
    constexpr int NCHUNK = CHA + 9 * S16B;
    constexpr int PSB_A = CIN0 * 2 + 8;
    constexpr int PSB_B = CIN1 * 2 + 8;
    constexpr int SROWS = ROWS + 2;
    constexpr int NMT   = 2 * ROWS;
    constexpr int NW_N  = (NT32 < WAVES) ? NT32 : WAVES;
    constexpr int NW_M  = WAVES / NW_N;
    constexpr int MT_W  = NMT / NW_M;
    constexpr int NTHR  = WAVES * 64;
    constexpr int LPSB  = (CIN1 > 0 && PSB_B > PSB_A) ? PSB_B : PSB_A;
    static_assert(NMT % NW_M == 0, "bad wave geometry");

    const NP np   = P.n[blockIdx.y];
    const int tid  = threadIdx.x;
    const int lane = tid & 63;
    const int w    = tid >> 6;
    const int b  = blockIdx.x & 7;              // image -> XCD pinning
    const int y0 = (blockIdx.x >> 3) * ROWS;

    __shared__ __align__(16) char smem[SROWS * 66 * LPSB];

    // ---- wave tile assignment ----
    const int nt  = w % NW_N;
    const int wm  = w / NW_N;
    const int mt0 = wm * MT_W;
    const int lm = lane & 31;
    const int kg = lane >> 5;

    // ---- B-fragment ring: prologue loads before staging ----
    const bf16_t* wp0 = np.Wp + (size_t)nt * 512 + (size_t)lane * 8;
    bf16x8 ring[PF];
#pragma unroll
    for (int i = 0; i < PF; ++i)
        ring[i] = *(const bf16x8*)(wp0 + (size_t)i * (NT32 * 512));

    // ---- stage phase A ----
    stage_ph<CIN0, SROWS, NTHR>(np.A0, smem, b, y0, tid);
    __syncthreads();

    int ab[MT_W][3];
#pragma unroll
    for (int mi = 0; mi < MT_W; ++mi) {
        int mt = mt0 + mi;
#pragma unroll
        for (int kx = 0; kx < 3; ++kx)
            ab[mi][kx] = ((mt >> 1) * 66 + (mt & 1) * 32 + lm + kx) * PSB_A + kg * 16;
    }

    f32x16 acc[MT_W];
    {
        float bv = np.bias[nt * 32 + lm];
#pragma unroll
        for (int mi = 0; mi < MT_W; ++mi)
#pragma unroll
            for (int r = 0; r < 16; ++r) acc[mi][r] = bv;
    }

    // ---- phase A K-loop ----
#pragma unroll
    for (int ch = 0; ch < CHA; ++ch) {
        bf16x8 bcur = ring[ch % PF];
        if (ch + PF < NCHUNK)
            ring[ch % PF] = *(const bf16x8*)(wp0 + (size_t)(ch + PF) * (NT32 * 512));
        const int tap = ch / S16A, kc = ch - tap * S16A;
        const int ky = tap / 3, kx = tap - 3 * (tap / 3);
#pragma unroll
        for (int mi = 0; mi < MT_W; ++mi) {
            bf16x8 a = *(const bf16x8*)(smem + ab[mi][kx] + (ky * 66 * PSB_A + kc * 32));
            acc[mi] = __builtin_amdgcn_mfma_f32_32x32x16_bf16(a, bcur, acc[mi], 0, 0, 0);
        }
    }

    // ---- phase B: restage same buffer with A1, continue K ----
    if constexpr (CIN1 > 0) {
        __syncthreads();   // all waves done reading phase-A LDS
        stage_ph<CIN1, SROWS, NTHR>(np.A1, smem, b, y0, tid);
        __syncthreads();
#pragma unroll
        for (int mi = 0; mi < MT_W; ++mi) {
            int mt = mt0 + mi;
#pragma unroll
            for (int kx = 0; kx < 3; ++kx)
                ab[mi][kx] = ((mt >> 1) * 66 + (mt & 1) * 32 + lm + kx) * PSB_B + kg * 16;
        }
#pragma unroll
        for (int ch = CHA; ch < NCHUNK; ++ch) {
            bf16x8 bcur = ring[ch % PF];
            if (ch + PF < NCHUNK)
                ring[ch % PF] = *(const bf16x8*)(wp0 + (size_t)(ch + PF) * (NT32 * 512));
            const int c2 = ch - CHA;
            const int tap = c2 / S16B, kc = c2 - tap * S16B;
            const int ky = tap / 3, kx = tap - 3 * (tap / 3);
#pragma unroll
            for (int mi = 0; mi < MT_W; ++mi) {
                bf16x8 a = *(const bf16x8*)(smem + ab[mi][kx] + (ky * 66 * PSB_B + kc * 32));
                acc[mi] = __builtin_amdgcn_mfma_f32_32x32x16_bf16(a, bcur, acc[mi], 0, 0, 0);
            }
        }
    }

    // ---- epilogue ----
    const int co = nt * 32 + lm;
#pragma unroll
    for (int mi = 0; mi < MT_W; ++mi) {
        int mt = mt0 + mi;
        int oy = y0 + (mt >> 1);
        int xb0 = (mt & 1) * 32;
#pragma unroll
        for (int reg = 0; reg < 16; ++reg) {
            int pxl = (reg & 3) + 8 * (reg >> 2) + 4 * kg;
            long pix = ((long)b * 64 + oy) * 64 + xb0 + pxl;
            float v = acc[mi][reg];
            if (MODE == 0) {
                np.outB[pix * COUT + co] = (bf16_t)v;
            } else if (MODE == 1) {
                float s = fsigmoid(v);
                if (co < HID) {
                    float hv = (float)np.Hb[pix * HID + co];
                    np.outB[pix * HID + co] = (bf16_t)(s * hv);   // rh
                } else {
                    np.outF[pix * HID + (co - HID)] = s;          // z
                }
            } else {
                float cd = ftanh(v);
                float z  = np.Zf[pix * HID + co];
                float ho = np.Hf[pix * HID + co];
                float hn = z * ho + (1.0f - z) * cd;
                np.outF[pix * HID + co] = hn;
                np.outB[pix * HID + co] = (bf16_t)hn;
            }
        }
    }
}

// ---------------------------------------------------------------------------
extern "C" void kernel_launch(void* const* d_in, const int* in_sizes, int n_in,
                              void* d_out, int out_size, void* d_ws, size_t ws_size,
                              hipStream_t stream) {
    const float* x    = (const float*)d_in[0];
    const float* Win0 = (const float*)d_in[1];
    const float* bin0 = (const float*)d_in[2];
    const float* We10 = (const float*)d_in[3];
    const float* be10 = (const float*)d_in[4];
    const float* We21 = (const float*)d_in[5];
    const float* be21 = (const float*)d_in[6];
    const float* Wint[3] = {(const float*)d_in[7],  (const float*)d_in[13], (const float*)d_in[19]};
    const float* bint[3] = {(const float*)d_in[8],  (const float*)d_in[14], (const float*)d_in[20]};
    const float* Wg[3]   = {(const float*)d_in[9],  (const float*)d_in[15], (const float*)d_in[21]};
    const float* bg[3]   = {(const float*)d_in[10], (const float*)d_in[16], (const float*)d_in[22]};
    const float* Wc[3]   = {(const float*)d_in[11], (const float*)d_in[17], (const float*)d_in[23]};
    const float* bc[3]   = {(const float*)d_in[12], (const float*)d_in[18], (const float*)d_in[24]};
    (void)in_sizes; (void)n_in; (void)out_size; (void)ws_size;

    const long PIX  = (long)BATCH * HH * WW;      // 32768
    const size_t HFSZ = (size_t)PIX * HID * 4;    // 8 MB
    const size_t HBSZ = (size_t)PIX * HID * 2;    // 4 MB
    const size_t XZSZ = (size_t)PIX * 64 * 2;     // 4 MB
    const long PSZ  = PIX * 32;                   // bf16 elems
    const long RHSZ = PIX * HID;
    const long ZSZ  = PIX * HID;

    char* wsb = (char*)d_ws;
    size_t off = 0;
    auto alloc = [&](size_t bytes) -> char* {
        char* q = wsb + off;
        off = (off + bytes + 255) & ~(size_t)255;
        return q;
    };

    // zero-group (contiguous)
    float*  hF[6]; bf16_t* hB[6];
    hF[0] = (float*)alloc(HFSZ); hF[1] = (float*)alloc(HFSZ); hF[2] = (float*)alloc(HFSZ);
    hB[0] = (bf16_t*)alloc(HBSZ); hB[1] = (bf16_t*)alloc(HBSZ); hB[2] = (bf16_t*)alloc(HBSZ);
    bf16_t* xzero = (bf16_t*)alloc(XZSZ);
    const size_t zeroBytes = 3 * HFSZ + 3 * HBSZ + XZSZ;
    // rest
    hF[3] = (float*)alloc(HFSZ); hF[4] = (float*)alloc(HFSZ); hF[5] = (float*)alloc(HFSZ);
    hB[3] = (bf16_t*)alloc(HBSZ); hB[4] = (bf16_t*)alloc(HBSZ); hB[5] = (bf16_t*)alloc(HBSZ);
    bf16_t* xb = (bf16_t*)alloc((size_t)TSEQ * PIX * 64 * 2);
    bf16_t* p  = (bf16_t*)alloc((size_t)3 * PSZ * 2);
    bf16_t* bu = (bf16_t*)alloc((size_t)3 * PSZ * 2);
    bf16_t* rh = (bf16_t*)alloc((size_t)3 * RHSZ * 2);
    float*  zb = (float*) alloc((size_t)3 * ZSZ * 4);
    bf16_t* WpIn0 = (bf16_t*)alloc((size_t)18432 * 2);  // 9*4*1*512
    bf16_t* WpE10 = (bf16_t*)alloc((size_t)18432 * 2);
    bf16_t* WpE21 = (bf16_t*)alloc((size_t)18432 * 2);
    bf16_t* WpInt[3], *WpG[3], *WpC[3];
    for (int n = 0; n < 3; ++n) WpInt[n] = (bf16_t*)alloc((size_t)9216 * 2);   // 9*2*1*512
    for (int n = 0; n < 3; ++n) WpG[n]   = (bf16_t*)alloc((size_t)110592 * 2); // 9*6*4*512
    for (int n = 0; n < 3; ++n) WpC[n]   = (bf16_t*)alloc((size_t)55296 * 2);  // 9*6*2*512

    hipMemsetAsync(hF[0], 0, zeroBytes, stream);

    // ---- weight packing (one dispatch, phased chunk order for split segs) ----
    PackArgs PA{};
    int beg = 0;
    auto seg = [&](int i, const float* src, bf16_t* dst, int Cout, int CinPad, int CinReal, int s16) {
        PA.s[i] = {src, dst, Cout / 32, CinPad / 16, CinReal, s16, beg};
        beg += 9 * (CinPad / 16) * (Cout / 32) * 512;
    };
    seg(0, Win0, WpIn0, 32, 64, 3, 4);
    seg(1, We10, WpE10, 32, 64, 64, 4);
    seg(2, We21, WpE21, 32, 64, 64, 4);
    for (int n = 0; n < 3; ++n) seg(3 + n, Wint[n], WpInt[n], 32, 32, 32, 2);
    for (int n = 0; n < 3; ++n) seg(6 + n, Wg[n],   WpG[n],   128, 96, 96, 2);  // split bu|h
    for (int n = 0; n < 3; ++n) seg(9 + n, Wc[n],   WpC[n],   64, 96, 96, 2);   // split bu|rh
    PA.total = beg;
    wpack_all<<<(PA.total + 255) / 256, 256, 0, stream>>>(PA);
    xcvt_k<<<(8 * 8 * 64 * 64 * 64 + 255) / 256, 256, 0, stream>>>(x, xb);

    // ---- recurrence ----
    float*  hFc[3] = {hF[0], hF[1], hF[2]};
    float*  hFn[3] = {hF[3], hF[4], hF[5]};
    bf16_t* hBc[3] = {hB[0], hB[1], hB[2]};
    bf16_t* hBn[3] = {hB[3], hB[4], hB[5]};
    const bf16_t* WpE[2] = {WpE10, WpE21};
    const float*  beE[2] = {be10, be21};

    const int GX2 = BATCH * (HH / 2);   // 256 blocks (ROWS=2 kernels)
    const int GX1 = BATCH * HH;         // 512 blocks (ROWS=1 kernels)

    for (int t = 0; t < PT; ++t) {
        const int nAct = (t + 1 < 3) ? (t + 1) : 3;
        // proj: all active nodes in one dispatch (CIN=64), 256 thr, ROWS=2
        {
            NPs P{};
            P.n[0].A0 = (t < TSEQ) ? (xb + (long)t * PIX * 64) : xzero;
            P.n[0].Wp = WpIn0; P.n[0].bias = bin0; P.n[0].outB = p;
            for (int n = 1; n < nAct; ++n) {
                P.n[n].A0 = hBc[n - 1];
                P.n[n].Wp = WpE[n - 1]; P.n[n].bias = beE[n - 1];
                P.n[n].outB = p + (long)n * PSZ;
            }
            mconv<64, 0, 32, 0, 4, 2, 4, 4><<<dim3(GX2, nAct), dim3(256), 0, stream>>>(P);
        }
        // integrator (CIN=32), 256 thr, ROWS=2
        {
            NPs P{};
            for (int n = 0; n < nAct; ++n) {
                P.n[n].A0 = p + (long)n * PSZ;
                P.n[n].Wp = WpInt[n]; P.n[n].bias = bint[n];
                P.n[n].outB = bu + (long)n * PSZ;
            }
            mconv<32, 0, 32, 0, 4, 2, 4, 4><<<dim3(GX2, nAct), dim3(256), 0, stream>>>(P);
        }
        // gates (rh bf16 + z fp32), 256 thr, ROWS=1, phased staging
        {
            NPs P{};
            for (int n = 0; n < nAct; ++n) {
                P.n[n].A0 = bu + (long)n * PSZ; P.n[n].A1 = hBc[n]; P.n[n].Hb = hBc[n];
                P.n[n].Wp = WpG[n]; P.n[n].bias = bg[n];
                P.n[n].outB = rh + (long)n * RHSZ; P.n[n].outF = zb + (long)n * ZSZ;
            }
            mconv<32, 64, 128, 1, 4, 1, 5, 4><<<dim3(GX1, nAct), dim3(256), 0, stream>>>(P);
        }
        // cand + GRU update, 256 thr, ROWS=1, phased staging
        {
            NPs P{};
            for (int n = 0; n < nAct; ++n) {
                P.n[n].A0 = bu + (long)n * PSZ; P.n[n].A1 = rh + (long)n * RHSZ;
                P.n[n].Zf = zb + (long)n * ZSZ; P.n[n].Hf = hFc[n];
                P.n[n].Wp = WpC[n]; P.n[n].bias = bc[n];
                P.n[n].outB = hBn[n]; P.n[n].outF = hFn[n];
            }
            mconv<32, 64, 64, 2, 4, 1, 6, 8><<<dim3(GX1, nAct), dim3(256), 0, stream>>>(P);
        }
        for (int n = 0; n < nAct; ++n) {
            float* tf = hFc[n]; hFc[n] = hFn[n]; hFn[n] = tf;
            bf16_t* tb = hBc[n]; hBc[n] = hBn[n]; hBn[n] = tb;
        }
    }

    hout_k<<<(8 * 64 * 64 * 64 + 255) / 256, 256, 0, stream>>>(hFc[2], (float*)d_out);
}

// Round 9
// 853.345 us; speedup vs baseline: 2.0559x; 2.0559x over previous
//
#include <hip/hip_runtime.h>
#include <hip/hip_bf16.h>

#define BATCH 8
#define TSEQ 8
#define HH 64
#define WW 64
#define HID 64
#define PT 10   // T + NUM_NODE - 1

typedef __bf16 bf16_t;
typedef __bf16 bf16x8 __attribute__((ext_vector_type(8)));
typedef float  f32x16 __attribute__((ext_vector_type(16)));

// fast transcendentals (v_exp_f32 + v_rcp_f32)
__device__ __forceinline__ float fsigmoid(float v) {
    float e = __builtin_amdgcn_exp2f(-1.4426950408889634f * v);
    return __builtin_amdgcn_rcpf(1.0f + e);
}
__device__ __forceinline__ float ftanh(float v) {
    float e = __builtin_amdgcn_exp2f(2.8853900817779268f * v);   // e^(2v)
    return 1.0f - 2.0f * __builtin_amdgcn_rcpf(1.0f + e);
}

// ---------------------------------------------------------------------------
// Weight pack for 32x32x16 MFMA B-fragments (R4/R6 order):
//   dst[((chunk*NT32 + nt)*64 + lane)*8 + j],  chunk = tap*KC + kc
//     = w[co = nt*32 + (lane&31)][ci = kc*16 + (lane>>5)*8 + j][tap]
// ---------------------------------------------------------------------------
struct PackSeg { const float* src; bf16_t* dst; int NT32; int KC; int CinReal; int begin; };
struct PackArgs { PackSeg s[12]; int total; };

__global__ void wpack_all(PackArgs P) {
    int idx = blockIdx.x * 256 + threadIdx.x;
    if (idx >= P.total) return;
    int si = 0;
#pragma unroll
    for (int i = 1; i < 12; ++i) if (idx >= P.s[i].begin) si = i;
    PackSeg sg = P.s[si];
    int l = idx - sg.begin;
    int j    = l & 7;
    int lane = (l >> 3) & 63;
    int rest = l >> 9;
    int nt   = rest % sg.NT32;
    int chunk = rest / sg.NT32;
    int kc  = chunk % sg.KC;
    int tap = chunk / sg.KC;
    int co = nt * 32 + (lane & 31);
    int ci = kc * 16 + (lane >> 5) * 8 + j;
    float v = (ci < sg.CinReal) ? sg.src[((long)co * sg.CinReal + ci) * 9 + tap] : 0.0f;
    sg.dst[l] = (bf16_t)v;
}

// x (B,T,3,H,W) fp32 -> xb [t][b][y][x][64] bf16 (channels 3..63 zero)
__global__ void xcvt_k(const float* __restrict__ x, bf16_t* __restrict__ xb) {
    int idx = blockIdx.x * 256 + threadIdx.x;
    if (idx >= 8 * 8 * 64 * 64 * 64) return;
    int c  = idx & 63;
    int xx = (idx >> 6) & 63;
    int y  = (idx >> 12) & 63;
    int b  = (idx >> 18) & 7;
    int t  = idx >> 21;
    float v = 0.0f;
    if (c < 3) v = x[((((long)b * TSEQ + t) * 3 + c) * 64 + y) * 64 + xx];
    xb[idx] = (bf16_t)v;
}

// h fp32 NHWC -> NCHW fp32 out
__global__ void hout_k(const float* __restrict__ hf, float* __restrict__ out) {
    int idx = blockIdx.x * 256 + threadIdx.x;
    if (idx >= 8 * 64 * 64 * 64) return;
    int xx = idx & 63;
    int y  = (idx >> 6) & 63;
    int c  = (idx >> 12) & 63;
    int b  = idx >> 18;
    out[idx] = hf[((((long)b * 64 + y) * 64 + xx) * 64) + c];
}

// ---------------------------------------------------------------------------
// MFMA 32x32x16 implicit-GEMM 3x3 conv, ROWS=2 per block (M = 128 px).
// R4 geometry: 4 waves, hybrid 2Mx2N wave tiling (acc <= 64 VGPR).
// LDS: [4 rows][66 px][CIN*2+8 B] padded pixel stride (low-conflict, R7).
// B-fragments prefetched via PF-deep register ring (static indices, R6).
// blockIdx.x: b = &7 (XCD-pinned), ychunk = >>3. blockIdx.y: active-node idx.
// MODE 0: plain conv, out bf16 NHWC.
// MODE 1: gates (COUT=128): sigmoid; co<64 -> rh bf16 (= r*Hb), co>=64 -> z f32.
// MODE 2: cand (COUT=64): h_new = z*h + (1-z)*tanh; writes h fp32 + h bf16.
// ---------------------------------------------------------------------------
struct NP {
    const bf16_t* A0;
    const bf16_t* A1;
    const float*  Zf;
    const float*  Hf;
    const bf16_t* Hb;
    const bf16_t* Wp;
    const float*  bias;
    bf16_t* outB;
    float*  outF;
};
struct NPs { NP n[3]; };

template <int CIN0, int CIN1, int COUT, int MODE, int MINW>
__global__ __launch_bounds__(256, MINW) void mconv(NPs P)
{
    constexpr int CIN  = CIN0 + CIN1;
    constexpr int NT32 = COUT / 32;
    constexpr int NCH  = CIN / 8;
    constexpr int KC   = CIN / 16;
    constexpr int MT_W = (NT32 == 1) ? 1 : 2;   // M tiles per wave
    constexpr int NT_W = (NT32 == 4) ? 2 : 1;   // N tiles per wave
    constexpr int PSB  = CIN * 2 + 8;           // padded pixel stride, bytes
    constexpr int NCHUNK = 9 * KC;
    constexpr int PF   = 6;                     // B-fragment prefetch depth

    const NP np   = P.n[blockIdx.y];
    const int tid  = threadIdx.x;
    const int lane = tid & 63;
    const int w    = tid >> 6;
    const int b  = blockIdx.x & 7;            // image -> XCD pinning
    const int y0 = (blockIdx.x >> 3) * 2;     // 2 output rows per block

    __shared__ __align__(16) char smem[4 * 66 * PSB];

    // ---- wave tile assignment ----
    int mt0, nt0;
    if (NT32 == 4)      { mt0 = (w >> 1) * 2; nt0 = (w & 1) * 2; }
    else if (NT32 == 2) { mt0 = (w >> 1) * 2; nt0 = (w & 1);     }
    else                { mt0 = w;            nt0 = 0;           }
    const int lm = lane & 31;
    const int kg = lane >> 5;

    // ---- B-fragment ring: issue prologue loads BEFORE staging ----
    const bf16_t* wp0 = np.Wp + (size_t)nt0 * 512 + (size_t)lane * 8;
    bf16x8 ring[PF][NT_W];
#pragma unroll
    for (int i = 0; i < PF; ++i)
#pragma unroll
        for (int ni = 0; ni < NT_W; ++ni)
            ring[i][ni] = *(const bf16x8*)(wp0 + (size_t)i * (NT32 * 512) + ni * 512);

    // ---- stage 4 rows x 66 px x CIN into padded LDS ----
    for (int c = tid; c < 4 * 66 * NCH; c += 256) {
        int ry = c / (66 * NCH);
        int r  = c - ry * 66 * NCH;
        int px = r / NCH;
        int c2 = r - px * NCH;
        int gy = y0 + ry - 1, gx = px - 1;
        bf16x8 v = {};
        if ((unsigned)gy < 64u && (unsigned)gx < 64u) {
            long pix = ((long)b * 64 + gy) * 64 + gx;
            int ci = c2 * 8;
            if (CIN1 == 0 || ci < CIN0) v = *(const bf16x8*)(np.A0 + pix * CIN0 + ci);
            else                        v = *(const bf16x8*)(np.A1 + pix * CIN1 + (ci - CIN0));
        }
        *(bf16x8*)(smem + (ry * 66 + px) * PSB + c2 * 16) = v;
    }
    __syncthreads();

    // ---- per-(mi,kx) LDS base addresses (K-loop reads are base + imm) ----
    int abase[MT_W][3];
#pragma unroll
    for (int mi = 0; mi < MT_W; ++mi) {
        int mt = mt0 + mi;
#pragma unroll
        for (int kx = 0; kx < 3; ++kx)
            abase[mi][kx] = ((mt >> 1) * 66 + (mt & 1) * 32 + lm + kx) * PSB + kg * 16;
    }

    f32x16 acc[MT_W][NT_W];
#pragma unroll
    for (int mi = 0; mi < MT_W; ++mi)
#pragma unroll
        for (int ni = 0; ni < NT_W; ++ni) {
            float bv = np.bias[(nt0 + ni) * 32 + lm];
#pragma unroll
            for (int r = 0; r < 16; ++r) acc[mi][ni][r] = bv;
        }

    // ---- K loop: fully unrolled, ring-prefetched B, imm-offset A reads ----
#pragma unroll
    for (int ch = 0; ch < NCHUNK; ++ch) {
        const int tap = ch / KC, kc = ch % KC;
        const int ky = tap / 3, kx = tap % 3;
        bf16x8 bcur[NT_W];
#pragma unroll
        for (int ni = 0; ni < NT_W; ++ni) bcur[ni] = ring[ch % PF][ni];
        if (ch + PF < NCHUNK) {
#pragma unroll
            for (int ni = 0; ni < NT_W; ++ni)
                ring[ch % PF][ni] =
                    *(const bf16x8*)(wp0 + (size_t)(ch + PF) * (NT32 * 512) + ni * 512);
        }
#pragma unroll
        for (int mi = 0; mi < MT_W; ++mi) {
            bf16x8 a = *(const bf16x8*)(smem + abase[mi][kx]
                                        + (ky * 66 * PSB + kc * 32));
#pragma unroll
            for (int ni = 0; ni < NT_W; ++ni)
                acc[mi][ni] = __builtin_amdgcn_mfma_f32_32x32x16_bf16(
                    a, bcur[ni], acc[mi][ni], 0, 0, 0);
        }
    }

    // ---- epilogue ----
#pragma unroll
    for (int mi = 0; mi < MT_W; ++mi) {
        int mt = mt0 + mi;
        int oy = y0 + (mt >> 1);
        int xb0 = (mt & 1) * 32;
#pragma unroll
        for (int ni = 0; ni < NT_W; ++ni) {
            int co = (nt0 + ni) * 32 + lm;
#pragma unroll
            for (int reg = 0; reg < 16; ++reg) {
                int pxl = (reg & 3) + 8 * (reg >> 2) + 4 * kg;
                long pix = ((long)b * 64 + oy) * 64 + xb0 + pxl;
                float v = acc[mi][ni][reg];
                if (MODE == 0) {
                    np.outB[pix * COUT + co] = (bf16_t)v;
                } else if (MODE == 1) {
                    float s = fsigmoid(v);
                    if (co < HID) {
                        float hv = (float)np.Hb[pix * HID + co];
                        np.outB[pix * HID + co] = (bf16_t)(s * hv);   // rh
                    } else {
                        np.outF[pix * HID + (co - HID)] = s;          // z
                    }
                } else {
                    float cd = ftanh(v);
                    float z  = np.Zf[pix * HID + co];
                    float ho = np.Hf[pix * HID + co];
                    float hn = z * ho + (1.0f - z) * cd;
                    np.outF[pix * HID + co] = hn;
                    np.outB[pix * HID + co] = (bf16_t)hn;
                }
            }
        }
    }
}

// ---------------------------------------------------------------------------
extern "C" void kernel_launch(void* const* d_in, const int* in_sizes, int n_in,
                              void* d_out, int out_size, void* d_ws, size_t ws_size,
                              hipStream_t stream) {
    const float* x    = (const float*)d_in[0];
    const float* Win0 = (const float*)d_in[1];
    const float* bin0 = (const float*)d_in[2];
    const float* We10 = (const float*)d_in[3];
    const float* be10 = (const float*)d_in[4];
    const float* We21 = (const float*)d_in[5];
    const float* be21 = (const float*)d_in[6];
    const float* Wint[3] = {(const float*)d_in[7],  (const float*)d_in[13], (const float*)d_in[19]};
    const float* bint[3] = {(const float*)d_in[8],  (const float*)d_in[14], (const float*)d_in[20]};
    const float* Wg[3]   = {(const float*)d_in[9],  (const float*)d_in[15], (const float*)d_in[21]};
    const float* bg[3]   = {(const float*)d_in[10], (const float*)d_in[16], (const float*)d_in[22]};
    const float* Wc[3]   = {(const float*)d_in[11], (const float*)d_in[17], (const float*)d_in[23]};
    const float* bc[3]   = {(const float*)d_in[12], (const float*)d_in[18], (const float*)d_in[24]};
    (void)in_sizes; (void)n_in; (void)out_size; (void)ws_size;

    const long PIX  = (long)BATCH * HH * WW;      // 32768
    const size_t HFSZ = (size_t)PIX * HID * 4;    // 8 MB
    const size_t HBSZ = (size_t)PIX * HID * 2;    // 4 MB
    const long PSZ  = PIX * 32;                   // bf16 elems
    const long RHSZ = PIX * HID;
    const long ZSZ  = PIX * HID;

    char* wsb = (char*)d_ws;
    size_t off = 0;
    auto alloc = [&](size_t bytes) -> char* {
        char* q = wsb + off;
        off = (off + bytes + 255) & ~(size_t)255;
        return q;
    };

    // zero-group (contiguous)
    float*  hF[6]; bf16_t* hB[6];
    hF[0] = (float*)alloc(HFSZ); hF[1] = (float*)alloc(HFSZ); hF[2] = (float*)alloc(HFSZ);
    hB[0] = (bf16_t*)alloc(HBSZ); hB[1] = (bf16_t*)alloc(HBSZ); hB[2] = (bf16_t*)alloc(HBSZ);
    const size_t zeroBytes = 3 * HFSZ + 3 * HBSZ;
    // rest
    hF[3] = (float*)alloc(HFSZ); hF[4] = (float*)alloc(HFSZ); hF[5] = (float*)alloc(HFSZ);
    hB[3] = (bf16_t*)alloc(HBSZ); hB[4] = (bf16_t*)alloc(HBSZ); hB[5] = (bf16_t*)alloc(HBSZ);
    bf16_t* xb = (bf16_t*)alloc((size_t)TSEQ * PIX * 64 * 2);
    bf16_t* p  = (bf16_t*)alloc((size_t)3 * PSZ * 2);
    bf16_t* bu = (bf16_t*)alloc((size_t)3 * PSZ * 2);
    bf16_t* rh = (bf16_t*)alloc((size_t)3 * RHSZ * 2);
    float*  zb = (float*) alloc((size_t)3 * ZSZ * 4);
    bf16_t* WpIn0 = (bf16_t*)alloc((size_t)18432 * 2);  // 9*4*1*512
    bf16_t* WpE10 = (bf16_t*)alloc((size_t)18432 * 2);
    bf16_t* WpE21 = (bf16_t*)alloc((size_t)18432 * 2);
    bf16_t* WpInt[3], *WpG[3], *WpC[3];
    for (int n = 0; n < 3; ++n) WpInt[n] = (bf16_t*)alloc((size_t)9216 * 2);   // 9*2*1*512
    for (int n = 0; n < 3; ++n) WpG[n]   = (bf16_t*)alloc((size_t)110592 * 2); // 9*6*4*512
    for (int n = 0; n < 3; ++n) WpC[n]   = (bf16_t*)alloc((size_t)55296 * 2);  // 9*6*2*512

    hipMemsetAsync(hF[0], 0, zeroBytes, stream);

    // ---- weight packing (one dispatch) ----
    PackArgs PA{};
    int beg = 0;
    auto seg = [&](int i, const float* src, bf16_t* dst, int Cout, int CinPad, int CinReal) {
        PA.s[i] = {src, dst, Cout / 32, CinPad / 16, CinReal, beg};
        beg += 9 * (CinPad / 16) * (Cout / 32) * 512;
    };
    seg(0, Win0, WpIn0, 32, 64, 3);
    seg(1, We10, WpE10, 32, 64, 64);
    seg(2, We21, WpE21, 32, 64, 64);
    for (int n = 0; n < 3; ++n) seg(3 + n, Wint[n], WpInt[n], 32, 32, 32);
    for (int n = 0; n < 3; ++n) seg(6 + n, Wg[n],   WpG[n],   128, 96, 96);
    for (int n = 0; n < 3; ++n) seg(9 + n, Wc[n],   WpC[n],   64, 96, 96);
    PA.total = beg;
    wpack_all<<<(PA.total + 255) / 256, 256, 0, stream>>>(PA);
    xcvt_k<<<(8 * 8 * 64 * 64 * 64 + 255) / 256, 256, 0, stream>>>(x, xb);

    // ---- recurrence ----
    // Dead-step elimination: node n only needs updates at t = n .. n+7
    // (later updates are never read by the output path).
    float*  hFc[3] = {hF[0], hF[1], hF[2]};
    float*  hFn[3] = {hF[3], hF[4], hF[5]};
    bf16_t* hBc[3] = {hB[0], hB[1], hB[2]};
    bf16_t* hBn[3] = {hB[3], hB[4], hB[5]};
    const bf16_t* WpE[2] = {WpE10, WpE21};
    const float*  beE[2] = {be10, be21};

    const dim3 T(256);
    const int GX = BATCH * (HH / 2);   // 256 blocks (2 rows per block)

    for (int t = 0; t < PT; ++t) {
        const int nLo = (t > 7) ? (t - 7) : 0;
        const int nHi = (t < 2) ? t : 2;
        const int nAct = nHi - nLo + 1;
        // proj: all active nodes in one dispatch (CIN=64)
        {
            NPs P{};
            for (int i = 0; i < nAct; ++i) {
                int n = nLo + i;
                if (n == 0) {
                    P.n[i].A0 = xb + (long)t * PIX * 64;       // t <= 7 when node0 active
                    P.n[i].Wp = WpIn0; P.n[i].bias = bin0;
                } else {
                    P.n[i].A0 = hBc[n - 1];
                    P.n[i].Wp = WpE[n - 1]; P.n[i].bias = beE[n - 1];
                }
                P.n[i].outB = p + (long)n * PSZ;
            }
            mconv<64, 0, 32, 0, 3><<<dim3(GX, nAct), T, 0, stream>>>(P);
        }
        // integrator
        {
            NPs P{};
            for (int i = 0; i < nAct; ++i) {
                int n = nLo + i;
                P.n[i].A0 = p + (long)n * PSZ;
                P.n[i].Wp = WpInt[n]; P.n[i].bias = bint[n];
                P.n[i].outB = bu + (long)n * PSZ;
            }
            mconv<32, 0, 32, 0, 4><<<dim3(GX, nAct), T, 0, stream>>>(P);
        }
        // gates (rh bf16 + z fp32)
        {
            NPs P{};
            for (int i = 0; i < nAct; ++i) {
                int n = nLo + i;
                P.n[i].A0 = bu + (long)n * PSZ; P.n[i].A1 = hBc[n]; P.n[i].Hb = hBc[n];
                P.n[i].Wp = WpG[n]; P.n[i].bias = bg[n];
                P.n[i].outB = rh + (long)n * RHSZ; P.n[i].outF = zb + (long)n * ZSZ;
            }
            mconv<32, 64, 128, 1, 3><<<dim3(GX, nAct), T, 0, stream>>>(P);
        }
        // cand + GRU update
        {
            NPs P{};
            for (int i = 0; i < nAct; ++i) {
                int n = nLo + i;
                P.n[i].A0 = bu + (long)n * PSZ; P.n[i].A1 = rh + (long)n * RHSZ;
                P.n[i].Zf = zb + (long)n * ZSZ; P.n[i].Hf = hFc[n];
                P.n[i].Wp = WpC[n]; P.n[i].bias = bc[n];
                P.n[i].outB = hBn[n]; P.n[i].outF = hFn[n];
            }
            mconv<32, 64, 64, 2, 3><<<dim3(GX, nAct), T, 0, stream>>>(P);
        }
        for (int n = nLo; n <= nHi; ++n) {
            float* tf = hFc[n]; hFc[n] = hFn[n]; hFn[n] = tf;
            bf16_t* tb = hBc[n]; hBc[n] = hBn[n]; hBn[n] = tb;
        }
    }

    hout_k<<<(8 * 64 * 64 * 64 + 255) / 256, 256, 0, stream>>>(hFc[2], (float*)d_out);
}

// Round 10
// 829.973 us; speedup vs baseline: 2.1138x; 1.0282x over previous
//
#include <hip/hip_runtime.h>
#include <hip/hip_bf16.h>

#define BATCH 8
#define TSEQ 8
#define HH 64
#define WW 64
#define HID 64
#define PT 10   // T + NUM_NODE - 1

typedef __bf16 bf16_t;
typedef __bf16 bf16x8 __attribute__((ext_vector_type(8)));
typedef float  f32x4  __attribute__((ext_vector_type(4)));

// fast transcendentals (v_exp_f32 + v_rcp_f32)
__device__ __forceinline__ float fsigmoid(float v) {
    float e = __builtin_amdgcn_exp2f(-1.4426950408889634f * v);
    return __builtin_amdgcn_rcpf(1.0f + e);
}
__device__ __forceinline__ float ftanh(float v) {
    float e = __builtin_amdgcn_exp2f(2.8853900817779268f * v);   // e^(2v)
    return 1.0f - 2.0f * __builtin_amdgcn_rcpf(1.0f + e);
}

// ---------------------------------------------------------------------------
// Weight pack for 16x16x32 MFMA B-fragments:
//   dst[((chunk*NT16 + nt)*64 + lane)*8 + j],  chunk = tap*KC + kc   (KC = CinPad/32)
//     = w[co = nt*16 + (lane&15)][ci = kc*32 + (lane>>4)*8 + j][tap]
// ---------------------------------------------------------------------------
struct PackSeg { const float* src; bf16_t* dst; int NT16; int KC; int CinReal; int begin; };
struct PackArgs { PackSeg s[12]; int total; };

__global__ void wpack_all(PackArgs P) {
    int idx = blockIdx.x * 256 + threadIdx.x;
    if (idx >= P.total) return;
    int si = 0;
#pragma unroll
    for (int i = 1; i < 12; ++i) if (idx >= P.s[i].begin) si = i;
    PackSeg sg = P.s[si];
    int l = idx - sg.begin;
    int j    = l & 7;
    int lane = (l >> 3) & 63;
    int rest = l >> 9;
    int nt   = rest % sg.NT16;
    int chunk = rest / sg.NT16;
    int kc  = chunk % sg.KC;
    int tap = chunk / sg.KC;
    int co = nt * 16 + (lane & 15);
    int ci = kc * 32 + (lane >> 4) * 8 + j;
    float v = (ci < sg.CinReal) ? sg.src[((long)co * sg.CinReal + ci) * 9 + tap] : 0.0f;
    sg.dst[l] = (bf16_t)v;
}

// x (B,T,3,H,W) fp32 -> xb [t][b][y][x][64] bf16 (channels 3..63 zero)
__global__ void xcvt_k(const float* __restrict__ x, bf16_t* __restrict__ xb) {
    int idx = blockIdx.x * 256 + threadIdx.x;
    if (idx >= 8 * 8 * 64 * 64 * 64) return;
    int c  = idx & 63;
    int xx = (idx >> 6) & 63;
    int y  = (idx >> 12) & 63;
    int b  = (idx >> 18) & 7;
    int t  = idx >> 21;
    float v = 0.0f;
    if (c < 3) v = x[((((long)b * TSEQ + t) * 3 + c) * 64 + y) * 64 + xx];
    xb[idx] = (bf16_t)v;
}

// h fp32 NHWC -> NCHW fp32 out
__global__ void hout_k(const float* __restrict__ hf, float* __restrict__ out) {
    int idx = blockIdx.x * 256 + threadIdx.x;
    if (idx >= 8 * 64 * 64 * 64) return;
    int xx = idx & 63;
    int y  = (idx >> 6) & 63;
    int c  = (idx >> 12) & 63;
    int b  = idx >> 18;
    out[idx] = hf[((((long)b * 64 + y) * 64 + xx) * 64) + c];
}

// ---------------------------------------------------------------------------
// MFMA 16x16x32 implicit-GEMM 3x3 conv, ROWS=2 per block (M = 128 px = 8 m16).
// K-chunk = 32 channels -> HALF the serial chunk depth of the 32x32x16 form
// (R4-R9 data: dur ~ 0.9us x NCHUNK, latency-bound on the chunk chain).
// Wave w: nt0 = (w % NW_N)*NT_W (n16 tiles), sweeps MT_W m16 tiles.
// LDS: [4 rows][66 px][CIN*2+8 B]; ds_read addr = 3 base VGPRs + 16-bit imm.
// blockIdx.x: b = &7 (XCD-pinned), ychunk = >>3. blockIdx.y: active-node idx.
// MODE 0: plain conv, out bf16 NHWC.
// MODE 1: gates (COUT=128): sigmoid; co<64 -> rh bf16 (= r*Hb), co>=64 -> z f32.
// MODE 2: cand (COUT=64): h_new = z*h + (1-z)*tanh; writes h fp32 + h bf16.
// ---------------------------------------------------------------------------
struct NP {
    const bf16_t* A0;
    const bf16_t* A1;
    const float*  Zf;
    const float*  Hf;
    const bf16_t* Hb;
    const bf16_t* Wp;
    const float*  bias;
    bf16_t* outB;
    float*  outF;
};
struct NPs { NP n[3]; };

template <int CIN0, int CIN1, int COUT, int MODE, int MINW>
__global__ __launch_bounds__(256, MINW) void mconv(NPs P)
{
    constexpr int CIN  = CIN0 + CIN1;
    constexpr int NT16 = COUT / 16;
    constexpr int NCH  = CIN / 8;
    constexpr int KC   = CIN / 32;              // K32 chunks per tap
    constexpr int NCHUNK = 9 * KC;
    constexpr int PSB  = CIN * 2 + 8;           // padded pixel stride, bytes
    constexpr int NT_W = (NT16 > 4) ? NT16 / 4 : 1;   // n16 tiles per wave
    constexpr int NW_N = NT16 / NT_W;           // waves across N
    constexpr int NW_M = 4 / NW_N;              // waves across M
    constexpr int MT_W = 8 / NW_M;              // m16 tiles per wave (NMT = 8)
    constexpr int PF   = 4;                     // B-fragment prefetch depth

    const NP np   = P.n[blockIdx.y];
    const int tid  = threadIdx.x;
    const int lane = tid & 63;
    const int w    = tid >> 6;
    const int b  = blockIdx.x & 7;              // image -> XCD pinning
    const int y0 = (blockIdx.x >> 3) * 2;       // 2 output rows per block

    __shared__ __align__(16) char smem[4 * 66 * PSB];

    // ---- wave tile assignment ----
    const int nt0 = (w % NW_N) * NT_W;
    const int mt0 = (w / NW_N) * MT_W;
    const int l15 = lane & 15;
    const int kg  = lane >> 4;                  // k-group 0..3 (8 ch each)

    // ---- B-fragment ring: issue prologue loads BEFORE staging ----
    const bf16_t* wp0 = np.Wp + (size_t)nt0 * 512 + (size_t)lane * 8;
    bf16x8 ring[PF][NT_W];
#pragma unroll
    for (int i = 0; i < PF; ++i)
#pragma unroll
        for (int ni = 0; ni < NT_W; ++ni)
            ring[i][ni] = *(const bf16x8*)(wp0 + (size_t)i * (NT16 * 512) + ni * 512);

    // ---- stage 4 rows x 66 px x CIN into padded LDS ----
    for (int c = tid; c < 4 * 66 * NCH; c += 256) {
        int ry = c / (66 * NCH);
        int r  = c - ry * 66 * NCH;
        int px = r / NCH;
        int c2 = r - px * NCH;
        int gy = y0 + ry - 1, gx = px - 1;
        bf16x8 v = {};
        if ((unsigned)gy < 64u && (unsigned)gx < 64u) {
            long pix = ((long)b * 64 + gy) * 64 + gx;
            int ci = c2 * 8;
            if (CIN1 == 0 || ci < CIN0) v = *(const bf16x8*)(np.A0 + pix * CIN0 + ci);
            else                        v = *(const bf16x8*)(np.A1 + pix * CIN1 + (ci - CIN0));
        }
        *(bf16x8*)(smem + (ry * 66 + px) * PSB + c2 * 16) = v;
    }
    __syncthreads();

    // ---- per-kx lane base addresses; everything else is a 16-bit immediate ----
    int ab[3];
#pragma unroll
    for (int kx = 0; kx < 3; ++kx)
        ab[kx] = (l15 + kx) * PSB + kg * 16;

    f32x4 acc[MT_W][NT_W];
#pragma unroll
    for (int mi = 0; mi < MT_W; ++mi)
#pragma unroll
        for (int ni = 0; ni < NT_W; ++ni) {
            float bv = np.bias[(nt0 + ni) * 16 + l15];
            acc[mi][ni] = (f32x4){bv, bv, bv, bv};
        }

    // ---- K loop: fully unrolled, ring-prefetched B, imm-offset A reads ----
#pragma unroll
    for (int ch = 0; ch < NCHUNK; ++ch) {
        const int tap = ch / KC, kc = ch % KC;
        const int ky = tap / 3, kx = tap % 3;
        bf16x8 bcur[NT_W];
#pragma unroll
        for (int ni = 0; ni < NT_W; ++ni) bcur[ni] = ring[ch % PF][ni];
        if (ch + PF < NCHUNK) {
#pragma unroll
            for (int ni = 0; ni < NT_W; ++ni)
                ring[ch % PF][ni] =
                    *(const bf16x8*)(wp0 + (size_t)(ch + PF) * (NT16 * 512) + ni * 512);
        }
#pragma unroll
        for (int mi = 0; mi < MT_W; ++mi) {
            const int mt = mt0 + mi;
            const int row = mt >> 2, xseg = mt & 3;
            const int imm = (row + ky) * (66 * PSB) + xseg * (16 * PSB) + kc * 64;
            bf16x8 a = *(const bf16x8*)(smem + ab[kx] + imm);
#pragma unroll
            for (int ni = 0; ni < NT_W; ++ni)
                acc[mi][ni] = __builtin_amdgcn_mfma_f32_16x16x32_bf16(
                    a, bcur[ni], acc[mi][ni], 0, 0, 0);
        }
    }

    // ---- epilogue: C/D layout col=lane&15 (=co), row=(lane>>4)*4+reg (=px) ----
#pragma unroll
    for (int mi = 0; mi < MT_W; ++mi) {
        const int mt = mt0 + mi;
        const int oy = y0 + (mt >> 2);
        const int xb0 = (mt & 3) * 16;
#pragma unroll
        for (int ni = 0; ni < NT_W; ++ni) {
            const int co = (nt0 + ni) * 16 + l15;
#pragma unroll
            for (int reg = 0; reg < 4; ++reg) {
                const int px = xb0 + kg * 4 + reg;
                long pix = ((long)b * 64 + oy) * 64 + px;
                float v = acc[mi][ni][reg];
                if (MODE == 0) {
                    np.outB[pix * COUT + co] = (bf16_t)v;
                } else if (MODE == 1) {
                    float s = fsigmoid(v);
                    if (co < HID) {
                        float hv = (float)np.Hb[pix * HID + co];
                        np.outB[pix * HID + co] = (bf16_t)(s * hv);   // rh
                    } else {
                        np.outF[pix * HID + (co - HID)] = s;          // z
                    }
                } else {
                    float cd = ftanh(v);
                    float z  = np.Zf[pix * HID + co];
                    float ho = np.Hf[pix * HID + co];
                    float hn = z * ho + (1.0f - z) * cd;
                    np.outF[pix * HID + co] = hn;
                    np.outB[pix * HID + co] = (bf16_t)hn;
                }
            }
        }
    }
}

// ---------------------------------------------------------------------------
extern "C" void kernel_launch(void* const* d_in, const int* in_sizes, int n_in,
                              void* d_out, int out_size, void* d_ws, size_t ws_size,
                              hipStream_t stream) {
    const float* x    = (const float*)d_in[0];
    const float* Win0 = (const float*)d_in[1];
    const float* bin0 = (const float*)d_in[2];
    const float* We10 = (const float*)d_in[3];
    const float* be10 = (const float*)d_in[4];
    const float* We21 = (const float*)d_in[5];
    const float* be21 = (const float*)d_in[6];
    const float* Wint[3] = {(const float*)d_in[7],  (const float*)d_in[13], (const float*)d_in[19]};
    const float* bint[3] = {(const float*)d_in[8],  (const float*)d_in[14], (const float*)d_in[20]};
    const float* Wg[3]   = {(const float*)d_in[9],  (const float*)d_in[15], (const float*)d_in[21]};
    const float* bg[3]   = {(const float*)d_in[10], (const float*)d_in[16], (const float*)d_in[22]};
    const float* Wc[3]   = {(const float*)d_in[11], (const float*)d_in[17], (const float*)d_in[23]};
    const float* bc[3]   = {(const float*)d_in[12], (const float*)d_in[18], (const float*)d_in[24]};
    (void)in_sizes; (void)n_in; (void)out_size; (void)ws_size;

    const long PIX  = (long)BATCH * HH * WW;      // 32768
    const size_t HFSZ = (size_t)PIX * HID * 4;    // 8 MB
    const size_t HBSZ = (size_t)PIX * HID * 2;    // 4 MB
    const long PSZ  = PIX * 32;                   // bf16 elems
    const long RHSZ = PIX * HID;
    const long ZSZ  = PIX * HID;

    char* wsb = (char*)d_ws;
    size_t off = 0;
    auto alloc = [&](size_t bytes) -> char* {
        char* q = wsb + off;
        off = (off + bytes + 255) & ~(size_t)255;
        return q;
    };

    // zero-group (contiguous)
    float*  hF[6]; bf16_t* hB[6];
    hF[0] = (float*)alloc(HFSZ); hF[1] = (float*)alloc(HFSZ); hF[2] = (float*)alloc(HFSZ);
    hB[0] = (bf16_t*)alloc(HBSZ); hB[1] = (bf16_t*)alloc(HBSZ); hB[2] = (bf16_t*)alloc(HBSZ);
    const size_t zeroBytes = 3 * HFSZ + 3 * HBSZ;
    // rest
    hF[3] = (float*)alloc(HFSZ); hF[4] = (float*)alloc(HFSZ); hF[5] = (float*)alloc(HFSZ);
    hB[3] = (bf16_t*)alloc(HBSZ); hB[4] = (bf16_t*)alloc(HBSZ); hB[5] = (bf16_t*)alloc(HBSZ);
    bf16_t* xb = (bf16_t*)alloc((size_t)TSEQ * PIX * 64 * 2);
    bf16_t* p  = (bf16_t*)alloc((size_t)3 * PSZ * 2);
    bf16_t* bu = (bf16_t*)alloc((size_t)3 * PSZ * 2);
    bf16_t* rh = (bf16_t*)alloc((size_t)3 * RHSZ * 2);
    float*  zb = (float*) alloc((size_t)3 * ZSZ * 4);
    bf16_t* WpIn0 = (bf16_t*)alloc((size_t)18432 * 2);  // 9*2*2*512
    bf16_t* WpE10 = (bf16_t*)alloc((size_t)18432 * 2);
    bf16_t* WpE21 = (bf16_t*)alloc((size_t)18432 * 2);
    bf16_t* WpInt[3], *WpG[3], *WpC[3];
    for (int n = 0; n < 3; ++n) WpInt[n] = (bf16_t*)alloc((size_t)9216 * 2);   // 9*1*2*512
    for (int n = 0; n < 3; ++n) WpG[n]   = (bf16_t*)alloc((size_t)110592 * 2); // 9*3*8*512
    for (int n = 0; n < 3; ++n) WpC[n]   = (bf16_t*)alloc((size_t)55296 * 2);  // 9*3*4*512

    hipMemsetAsync(hF[0], 0, zeroBytes, stream);

    // ---- weight packing (one dispatch) ----
    PackArgs PA{};
    int beg = 0;
    auto seg = [&](int i, const float* src, bf16_t* dst, int Cout, int CinPad, int CinReal) {
        PA.s[i] = {src, dst, Cout / 16, CinPad / 32, CinReal, beg};
        beg += 9 * (CinPad / 32) * (Cout / 16) * 512;
    };
    seg(0, Win0, WpIn0, 32, 64, 3);
    seg(1, We10, WpE10, 32, 64, 64);
    seg(2, We21, WpE21, 32, 64, 64);
    for (int n = 0; n < 3; ++n) seg(3 + n, Wint[n], WpInt[n], 32, 32, 32);
    for (int n = 0; n < 3; ++n) seg(6 + n, Wg[n],   WpG[n],   128, 96, 96);
    for (int n = 0; n < 3; ++n) seg(9 + n, Wc[n],   WpC[n],   64, 96, 96);
    PA.total = beg;
    wpack_all<<<(PA.total + 255) / 256, 256, 0, stream>>>(PA);
    xcvt_k<<<(8 * 8 * 64 * 64 * 64 + 255) / 256, 256, 0, stream>>>(x, xb);

    // ---- recurrence ----
    // Dead-step elimination: node n only needs updates at t = n .. n+7.
    float*  hFc[3] = {hF[0], hF[1], hF[2]};
    float*  hFn[3] = {hF[3], hF[4], hF[5]};
    bf16_t* hBc[3] = {hB[0], hB[1], hB[2]};
    bf16_t* hBn[3] = {hB[3], hB[4], hB[5]};
    const bf16_t* WpE[2] = {WpE10, WpE21};
    const float*  beE[2] = {be10, be21};

    const dim3 T(256);
    const int GX = BATCH * (HH / 2);   // 256 blocks (2 rows per block)

    for (int t = 0; t < PT; ++t) {
        const int nLo = (t > 7) ? (t - 7) : 0;
        const int nHi = (t < 2) ? t : 2;
        const int nAct = nHi - nLo + 1;
        // proj: all active nodes in one dispatch (CIN=64)
        {
            NPs P{};
            for (int i = 0; i < nAct; ++i) {
                int n = nLo + i;
                if (n == 0) {
                    P.n[i].A0 = xb + (long)t * PIX * 64;       // t <= 7 when node0 active
                    P.n[i].Wp = WpIn0; P.n[i].bias = bin0;
                } else {
                    P.n[i].A0 = hBc[n - 1];
                    P.n[i].Wp = WpE[n - 1]; P.n[i].bias = beE[n - 1];
                }
                P.n[i].outB = p + (long)n * PSZ;
            }
            mconv<64, 0, 32, 0, 3><<<dim3(GX, nAct), T, 0, stream>>>(P);
        }
        // integrator
        {
            NPs P{};
            for (int i = 0; i < nAct; ++i) {
                int n = nLo + i;
                P.n[i].A0 = p + (long)n * PSZ;
                P.n[i].Wp = WpInt[n]; P.n[i].bias = bint[n];
                P.n[i].outB = bu + (long)n * PSZ;
            }
            mconv<32, 0, 32, 0, 4><<<dim3(GX, nAct), T, 0, stream>>>(P);
        }
        // gates (rh bf16 + z fp32)
        {
            NPs P{};
            for (int i = 0; i < nAct; ++i) {
                int n = nLo + i;
                P.n[i].A0 = bu + (long)n * PSZ; P.n[i].A1 = hBc[n]; P.n[i].Hb = hBc[n];
                P.n[i].Wp = WpG[n]; P.n[i].bias = bg[n];
                P.n[i].outB = rh + (long)n * RHSZ; P.n[i].outF = zb + (long)n * ZSZ;
            }
            mconv<32, 64, 128, 1, 3><<<dim3(GX, nAct), T, 0, stream>>>(P);
        }
        // cand + GRU update
        {
            NPs P{};
            for (int i = 0; i < nAct; ++i) {
                int n = nLo + i;
                P.n[i].A0 = bu + (long)n * PSZ; P.n[i].A1 = rh + (long)n * RHSZ;
                P.n[i].Zf = zb + (long)n * ZSZ; P.n[i].Hf = hFc[n];
                P.n[i].Wp = WpC[n]; P.n[i].bias = bc[n];
                P.n[i].outB = hBn[n]; P.n[i].outF = hFn[n];
            }
            mconv<32, 64, 64, 2, 3><<<dim3(GX, nAct), T, 0, stream>>>(P);
        }
        for (int n = nLo; n <= nHi; ++n) {
            float* tf = hFc[n]; hFc[n] = hFn[n]; hFn[n] = tf;
            bf16_t* tb = hBc[n]; hBc[n] = hBn[n]; hBn[n] = tb;
        }
    }

    hout_k<<<(8 * 64 * 64 * 64 + 255) / 256, 256, 0, stream>>>(hFc[2], (float*)d_out);
}

// Round 12
// 764.437 us; speedup vs baseline: 2.2950x; 1.0857x over previous
//
#include <hip/hip_runtime.h>
#include <hip/hip_bf16.h>

#define BATCH 8
#define TSEQ 8
#define HH 64
#define WW 64
#define HID 64
#define PT 10   // T + NUM_NODE - 1

typedef __bf16 bf16_t;
typedef __bf16 bf16x8 __attribute__((ext_vector_type(8)));
typedef float  f32x4  __attribute__((ext_vector_type(4)));

// fast transcendentals (v_exp_f32 + v_rcp_f32)
__device__ __forceinline__ float fsigmoid(float v) {
    float e = __builtin_amdgcn_exp2f(-1.4426950408889634f * v);
    return __builtin_amdgcn_rcpf(1.0f + e);
}
__device__ __forceinline__ float ftanh(float v) {
    float e = __builtin_amdgcn_exp2f(2.8853900817779268f * v);   // e^(2v)
    return 1.0f - 2.0f * __builtin_amdgcn_rcpf(1.0f + e);
}

// ---------------------------------------------------------------------------
// Weight pack for 16x16x32 MFMA B-fragments (R10):
//   dst[((chunk*NT16 + nt)*64 + lane)*8 + j],  chunk = tap*KC + kc  (KC=CinPad/32)
//     = w[co = nt*16 + (lane&15)][ci = kc*32 + (lane>>4)*8 + j][tap]
// ---------------------------------------------------------------------------
struct PackSeg { const float* src; bf16_t* dst; int NT16; int KC; int CinReal; int begin; };
struct PackArgs { PackSeg s[12]; int total; };

__global__ void wpack_all(PackArgs P) {
    int idx = blockIdx.x * 256 + threadIdx.x;
    if (idx >= P.total) return;
    int si = 0;
#pragma unroll
    for (int i = 1; i < 12; ++i) if (idx >= P.s[i].begin) si = i;
    PackSeg sg = P.s[si];
    int l = idx - sg.begin;
    int j    = l & 7;
    int lane = (l >> 3) & 63;
    int rest = l >> 9;
    int nt   = rest % sg.NT16;
    int chunk = rest / sg.NT16;
    int kc  = chunk % sg.KC;
    int tap = chunk / sg.KC;
    int co = nt * 16 + (lane & 15);
    int ci = kc * 32 + (lane >> 4) * 8 + j;
    float v = (ci < sg.CinReal) ? sg.src[((long)co * sg.CinReal + ci) * 9 + tap] : 0.0f;
    sg.dst[l] = (bf16_t)v;
}

// x (B,T,3,H,W) fp32 -> xb [t][b][y][x][64] bf16 (channels 3..63 zero)
__global__ void xcvt_k(const float* __restrict__ x, bf16_t* __restrict__ xb) {
    int idx = blockIdx.x * 256 + threadIdx.x;
    if (idx >= 8 * 8 * 64 * 64 * 64) return;
    int c  = idx & 63;
    int xx = (idx >> 6) & 63;
    int y  = (idx >> 12) & 63;
    int b  = (idx >> 18) & 7;
    int t  = idx >> 21;
    float v = 0.0f;
    if (c < 3) v = x[((((long)b * TSEQ + t) * 3 + c) * 64 + y) * 64 + xx];
    xb[idx] = (bf16_t)v;
}

// h fp32 NHWC -> NCHW fp32 out
__global__ void hout_k(const float* __restrict__ hf, float* __restrict__ out) {
    int idx = blockIdx.x * 256 + threadIdx.x;
    if (idx >= 8 * 64 * 64 * 64) return;
    int xx = idx & 63;
    int y  = (idx >> 6) & 63;
    int c  = (idx >> 12) & 63;
    int b  = idx >> 18;
    out[idx] = hf[((((long)b * 64 + y) * 64 + xx) * 64) + c];
}

// ---------------------------------------------------------------------------
// MFMA 16x16x32 implicit-GEMM 3x3 conv, ROWS=2 per block (M = 128 px = 8 m16).
// NEW (R12): epilogue bounces outputs through LDS so global stores are full
// 128-B lines (R10 counters: scattered 2-B epilogue stores caused 3.3x HBM
// write amplification -> gates dispatch was HBM-bound at 40 MB writes).
// LDS staging strides: bf16 rows 72 elems (144 B, 16B-aligned), f32 rows 68.
// blockIdx.x: b = &7 (XCD-pinned), ychunk = >>3. blockIdx.y: active-node idx.
// MODE 0: plain conv -> bf16 NHWC.
// MODE 1: gates (COUT=128): sigmoid; co<64 -> rh bf16 (= r*Hb), co>=64 -> z f32.
// MODE 2: cand (COUT=64): h_new = z*h + (1-z)*tanh; writes h fp32 + h bf16.
// ---------------------------------------------------------------------------
struct NP {
    const bf16_t* A0;
    const bf16_t* A1;
    const float*  Zf;
    const float*  Hf;
    const bf16_t* Hb;
    const bf16_t* Wp;
    const float*  bias;
    bf16_t* outB;
    float*  outF;
};
struct NPs { NP n[3]; };

template <int CIN0, int CIN1, int COUT, int MODE, int MINW>
__global__ __launch_bounds__(256, MINW) void mconv(NPs P)
{
    constexpr int CIN  = CIN0 + CIN1;
    constexpr int NT16 = COUT / 16;
    constexpr int NCH  = CIN / 8;
    constexpr int KC   = CIN / 32;              // K32 chunks per tap
    constexpr int NCHUNK = 9 * KC;
    constexpr int PSB  = CIN * 2 + 8;           // padded pixel stride, bytes
    constexpr int NT_W = (NT16 > 4) ? NT16 / 4 : 1;   // n16 tiles per wave
    constexpr int NW_N = NT16 / NT_W;           // waves across N
    constexpr int NW_M = 4 / NW_N;              // waves across M
    constexpr int MT_W = 8 / NW_M;              // m16 tiles per wave (NMT = 8)
    constexpr int PF   = 4;                     // B-fragment prefetch depth
    // LDS sizing: A-tile vs output staging
    constexpr int ASMEM = 4 * 66 * PSB;
    constexpr int OSB   = COUT + 8;             // MODE0 bf16 stage stride
    constexpr int OSMEM = (MODE == 0) ? 128 * OSB * 2
                                      : 128 * 68 * 4 + 128 * 72 * 2;  // 53,248
    constexpr int SMEM  = (ASMEM > OSMEM) ? ASMEM : OSMEM;

    const NP np   = P.n[blockIdx.y];
    const int tid  = threadIdx.x;
    const int lane = tid & 63;
    const int w    = tid >> 6;
    const int b  = blockIdx.x & 7;              // image -> XCD pinning
    const int y0 = (blockIdx.x >> 3) * 2;       // 2 output rows per block

    __shared__ __align__(16) char smem[SMEM];

    // ---- wave tile assignment ----
    const int nt0 = (w % NW_N) * NT_W;
    const int mt0 = (w / NW_N) * MT_W;
    const int l15 = lane & 15;
    const int kg  = lane >> 4;                  // k-group 0..3 (8 ch each)

    // ---- B-fragment ring: issue prologue loads BEFORE staging ----
    const bf16_t* wp0 = np.Wp + (size_t)nt0 * 512 + (size_t)lane * 8;
    bf16x8 ring[PF][NT_W];
#pragma unroll
    for (int i = 0; i < PF; ++i)
#pragma unroll
        for (int ni = 0; ni < NT_W; ++ni)
            ring[i][ni] = *(const bf16x8*)(wp0 + (size_t)i * (NT16 * 512) + ni * 512);

    // ---- stage 4 rows x 66 px x CIN into padded LDS ----
    for (int c = tid; c < 4 * 66 * NCH; c += 256) {
        int ry = c / (66 * NCH);
        int r  = c - ry * 66 * NCH;
        int px = r / NCH;
        int c2 = r - px * NCH;
        int gy = y0 + ry - 1, gx = px - 1;
        bf16x8 v = {};
        if ((unsigned)gy < 64u && (unsigned)gx < 64u) {
            long pix = ((long)b * 64 + gy) * 64 + gx;
            int ci = c2 * 8;
            if (CIN1 == 0 || ci < CIN0) v = *(const bf16x8*)(np.A0 + pix * CIN0 + ci);
            else                        v = *(const bf16x8*)(np.A1 + pix * CIN1 + (ci - CIN0));
        }
        *(bf16x8*)(smem + (ry * 66 + px) * PSB + c2 * 16) = v;
    }
    __syncthreads();

    // ---- per-kx lane base addresses ----
    int ab[3];
#pragma unroll
    for (int kx = 0; kx < 3; ++kx)
        ab[kx] = (l15 + kx) * PSB + kg * 16;

    f32x4 acc[MT_W][NT_W];
#pragma unroll
    for (int mi = 0; mi < MT_W; ++mi)
#pragma unroll
        for (int ni = 0; ni < NT_W; ++ni) {
            float bv = np.bias[(nt0 + ni) * 16 + l15];
            acc[mi][ni] = (f32x4){bv, bv, bv, bv};
        }

    // ---- K loop: fully unrolled, ring-prefetched B, imm-offset A reads ----
#pragma unroll
    for (int ch = 0; ch < NCHUNK; ++ch) {
        const int tap = ch / KC, kc = ch % KC;
        const int ky = tap / 3, kx = tap % 3;
        bf16x8 bcur[NT_W];
#pragma unroll
        for (int ni = 0; ni < NT_W; ++ni) bcur[ni] = ring[ch % PF][ni];
        if (ch + PF < NCHUNK) {
#pragma unroll
            for (int ni = 0; ni < NT_W; ++ni)
                ring[ch % PF][ni] =
                    *(const bf16x8*)(wp0 + (size_t)(ch + PF) * (NT16 * 512) + ni * 512);
        }
#pragma unroll
        for (int mi = 0; mi < MT_W; ++mi) {
            const int mt = mt0 + mi;
            const int row = mt >> 2, xseg = mt & 3;
            const int imm = (row + ky) * (66 * PSB) + xseg * (16 * PSB) + kc * 64;
            bf16x8 a = *(const bf16x8*)(smem + ab[kx] + imm);
#pragma unroll
            for (int ni = 0; ni < NT_W; ++ni)
                acc[mi][ni] = __builtin_amdgcn_mfma_f32_16x16x32_bf16(
                    a, bcur[ni], acc[mi][ni], 0, 0, 0);
        }
    }

    // ---- epilogue: LDS-bounce for coalesced global stores ----
    // C/D layout: col = lane&15 (=co), row = (lane>>4)*4+reg (=px)
    __syncthreads();   // everyone done reading A-tiles; smem reused below
    const long pixbase = ((long)b * 64 + y0) * 64;   // 128 contiguous pixels

    if (MODE == 0) {
        bf16_t* so = (bf16_t*)smem;                  // [128][OSB]
#pragma unroll
        for (int mi = 0; mi < MT_W; ++mi) {
            const int mt = mt0 + mi;
            const int lpx0 = (mt >> 2) * 64 + (mt & 3) * 16 + kg * 4;
#pragma unroll
            for (int ni = 0; ni < NT_W; ++ni) {
                const int co = (nt0 + ni) * 16 + l15;
#pragma unroll
                for (int reg = 0; reg < 4; ++reg)
                    so[(lpx0 + reg) * OSB + co] = (bf16_t)acc[mi][ni][reg];
            }
        }
        __syncthreads();
        for (int i = tid; i < 128 * (COUT / 8); i += 256) {
            const int p = i / (COUT / 8);
            const int cc = (i % (COUT / 8)) * 8;
            *(bf16x8*)(np.outB + (pixbase + p) * COUT + cc) =
                *(const bf16x8*)(so + p * OSB + cc);
        }
    } else if (MODE == 1) {
        bf16_t* srh = (bf16_t*)smem;                         // [128][72] bf16
        float*  sz  = (float*)(smem + 128 * 72 * 2);         // [128][68] f32
#pragma unroll
        for (int mi = 0; mi < MT_W; ++mi) {
            const int mt = mt0 + mi;
            const int lpx0 = (mt >> 2) * 64 + (mt & 3) * 16 + kg * 4;
#pragma unroll
            for (int ni = 0; ni < NT_W; ++ni) {
                const int co = (nt0 + ni) * 16 + l15;
#pragma unroll
                for (int reg = 0; reg < 4; ++reg) {
                    const int lpx = lpx0 + reg;
                    float s = fsigmoid(acc[mi][ni][reg]);
                    if (co < HID) {
                        float hv = (float)np.Hb[(pixbase + lpx) * HID + co];
                        srh[lpx * 72 + co] = (bf16_t)(s * hv);   // rh
                    } else {
                        sz[lpx * 68 + (co - HID)] = s;           // z
                    }
                }
            }
        }
        __syncthreads();
        for (int i = tid; i < 128 * 8; i += 256) {           // rh: 8x bf16x8 per row
            const int p = i >> 3, cc = (i & 7) * 8;
            *(bf16x8*)(np.outB + (pixbase + p) * HID + cc) =
                *(const bf16x8*)(srh + p * 72 + cc);
        }
        for (int i = tid; i < 128 * 16; i += 256) {          // z: 16x float4 per row
            const int p = i >> 4, cc = (i & 15) * 4;
            *(f32x4*)(np.outF + (pixbase + p) * HID + cc) =
                *(const f32x4*)(sz + p * 68 + cc);
        }
    } else {
        float*  shf = (float*)smem;                          // [128][68] f32
        bf16_t* shb = (bf16_t*)(smem + 128 * 68 * 4);        // [128][72] bf16
#pragma unroll
        for (int mi = 0; mi < MT_W; ++mi) {
            const int mt = mt0 + mi;
            const int lpx0 = (mt >> 2) * 64 + (mt & 3) * 16 + kg * 4;
#pragma unroll
            for (int ni = 0; ni < NT_W; ++ni) {
                const int co = (nt0 + ni) * 16 + l15;
#pragma unroll
                for (int reg = 0; reg < 4; ++reg) {
                    const int lpx = lpx0 + reg;
                    float cd = ftanh(acc[mi][ni][reg]);
                    float z  = np.Zf[(pixbase + lpx) * HID + co];
                    float ho = np.Hf[(pixbase + lpx) * HID + co];
                    float hn = z * ho + (1.0f - z) * cd;
                    shf[lpx * 68 + co] = hn;
                    shb[lpx * 72 + co] = (bf16_t)hn;
                }
            }
        }
        __syncthreads();
        for (int i = tid; i < 128 * 16; i += 256) {          // h f32
            const int p = i >> 4, cc = (i & 15) * 4;
            *(f32x4*)(np.outF + (pixbase + p) * HID + cc) =
                *(const f32x4*)(shf + p * 68 + cc);
        }
        for (int i = tid; i < 128 * 8; i += 256) {           // h bf16
            const int p = i >> 3, cc = (i & 7) * 8;
            *(bf16x8*)(np.outB + (pixbase + p) * HID + cc) =
                *(const bf16x8*)(shb + p * 72 + cc);
        }
    }
}

// ---------------------------------------------------------------------------
extern "C" void kernel_launch(void* const* d_in, const int* in_sizes, int n_in,
                              void* d_out, int out_size, void* d_ws, size_t ws_size,
                              hipStream_t stream) {
    const float* x    = (const float*)d_in[0];
    const float* Win0 = (const float*)d_in[1];
    const float* bin0 = (const float*)d_in[2];
    const float* We10 = (const float*)d_in[3];
    const float* be10 = (const float*)d_in[4];
    const float* We21 = (const float*)d_in[5];
    const float* be21 = (const float*)d_in[6];
    const float* Wint[3] = {(const float*)d_in[7],  (const float*)d_in[13], (const float*)d_in[19]};
    const float* bint[3] = {(const float*)d_in[8],  (const float*)d_in[14], (const float*)d_in[20]};
    const float* Wg[3]   = {(const float*)d_in[9],  (const float*)d_in[15], (const float*)d_in[21]};
    const float* bg[3]   = {(const float*)d_in[10], (const float*)d_in[16], (const float*)d_in[22]};
    const float* Wc[3]   = {(const float*)d_in[11], (const float*)d_in[17], (const float*)d_in[23]};
    const float* bc[3]   = {(const float*)d_in[12], (const float*)d_in[18], (const float*)d_in[24]};
    (void)in_sizes; (void)n_in; (void)out_size; (void)ws_size;

    const long PIX  = (long)BATCH * HH * WW;      // 32768
    const size_t HFSZ = (size_t)PIX * HID * 4;    // 8 MB
    const size_t HBSZ = (size_t)PIX * HID * 2;    // 4 MB
    const long PSZ  = PIX * 32;                   // bf16 elems
    const long RHSZ = PIX * HID;
    const long ZSZ  = PIX * HID;

    char* wsb = (char*)d_ws;
    size_t off = 0;
    auto alloc = [&](size_t bytes) -> char* {
        char* q = wsb + off;
        off = (off + bytes + 255) & ~(size_t)255;
        return q;
    };

    // zero-group (contiguous)
    float*  hF[6]; bf16_t* hB[6];
    hF[0] = (float*)alloc(HFSZ); hF[1] = (float*)alloc(HFSZ); hF[2] = (float*)alloc(HFSZ);
    hB[0] = (bf16_t*)alloc(HBSZ); hB[1] = (bf16_t*)alloc(HBSZ); hB[2] = (bf16_t*)alloc(HBSZ);
    const size_t zeroBytes = 3 * HFSZ + 3 * HBSZ;
    // rest
    hF[3] = (float*)alloc(HFSZ); hF[4] = (float*)alloc(HFSZ); hF[5] = (float*)alloc(HFSZ);
    hB[3] = (bf16_t*)alloc(HBSZ); hB[4] = (bf16_t*)alloc(HBSZ); hB[5] = (bf16_t*)alloc(HBSZ);
    bf16_t* xb = (bf16_t*)alloc((size_t)TSEQ * PIX * 64 * 2);
    bf16_t* p  = (bf16_t*)alloc((size_t)3 * PSZ * 2);
    bf16_t* bu = (bf16_t*)alloc((size_t)3 * PSZ * 2);
    bf16_t* rh = (bf16_t*)alloc((size_t)3 * RHSZ * 2);
    float*  zb = (float*) alloc((size_t)3 * ZSZ * 4);
    bf16_t* WpIn0 = (bf16_t*)alloc((size_t)18432 * 2);  // 9*2*2*512
    bf16_t* WpE10 = (bf16_t*)alloc((size_t)18432 * 2);
    bf16_t* WpE21 = (bf16_t*)alloc((size_t)18432 * 2);
    bf16_t* WpInt[3], *WpG[3], *WpC[3];
    for (int n = 0; n < 3; ++n) WpInt[n] = (bf16_t*)alloc((size_t)9216 * 2);   // 9*1*2*512
    for (int n = 0; n < 3; ++n) WpG[n]   = (bf16_t*)alloc((size_t)110592 * 2); // 9*3*8*512
    for (int n = 0; n < 3; ++n) WpC[n]   = (bf16_t*)alloc((size_t)55296 * 2);  // 9*3*4*512

    hipMemsetAsync(hF[0], 0, zeroBytes, stream);

    // ---- weight packing (one dispatch) ----
    PackArgs PA{};
    int beg = 0;
    auto seg = [&](int i, const float* src, bf16_t* dst, int Cout, int CinPad, int CinReal) {
        PA.s[i] = {src, dst, Cout / 16, CinPad / 32, CinReal, beg};
        beg += 9 * (CinPad / 32) * (Cout / 16) * 512;
    };
    seg(0, Win0, WpIn0, 32, 64, 3);
    seg(1, We10, WpE10, 32, 64, 64);
    seg(2, We21, WpE21, 32, 64, 64);
    for (int n = 0; n < 3; ++n) seg(3 + n, Wint[n], WpInt[n], 32, 32, 32);
    for (int n = 0; n < 3; ++n) seg(6 + n, Wg[n],   WpG[n],   128, 96, 96);
    for (int n = 0; n < 3; ++n) seg(9 + n, Wc[n],   WpC[n],   64, 96, 96);
    PA.total = beg;
    wpack_all<<<(PA.total + 255) / 256, 256, 0, stream>>>(PA);
    xcvt_k<<<(8 * 8 * 64 * 64 * 64 + 255) / 256, 256, 0, stream>>>(x, xb);

    // ---- recurrence ----
    // Dead-step elimination: node n only needs updates at t = n .. n+7.
    float*  hFc[3] = {hF[0], hF[1], hF[2]};
    float*  hFn[3] = {hF[3], hF[4], hF[5]};
    bf16_t* hBc[3] = {hB[0], hB[1], hB[2]};
    bf16_t* hBn[3] = {hB[3], hB[4], hB[5]};
    const bf16_t* WpE[2] = {WpE10, WpE21};
    const float*  beE[2] = {be10, be21};

    const dim3 T(256);
    const int GX = BATCH * (HH / 2);   // 256 blocks (2 rows per block)

    for (int t = 0; t < PT; ++t) {
        const int nLo = (t > 7) ? (t - 7) : 0;
        const int nHi = (t < 2) ? t : 2;
        const int nAct = nHi - nLo + 1;
        // proj: all active nodes in one dispatch (CIN=64)
        {
            NPs P{};
            for (int i = 0; i < nAct; ++i) {
                int n = nLo + i;
                if (n == 0) {
                    P.n[i].A0 = xb + (long)t * PIX * 64;       // t <= 7 when node0 active
                    P.n[i].Wp = WpIn0; P.n[i].bias = bin0;
                } else {
                    P.n[i].A0 = hBc[n - 1];
                    P.n[i].Wp = WpE[n - 1]; P.n[i].bias = beE[n - 1];
                }
                P.n[i].outB = p + (long)n * PSZ;
            }
            mconv<64, 0, 32, 0, 3><<<dim3(GX, nAct), T, 0, stream>>>(P);
        }
        // integrator
        {
            NPs P{};
            for (int i = 0; i < nAct; ++i) {
                int n = nLo + i;
                P.n[i].A0 = p + (long)n * PSZ;
                P.n[i].Wp = WpInt[n]; P.n[i].bias = bint[n];
                P.n[i].outB = bu + (long)n * PSZ;
            }
            mconv<32, 0, 32, 0, 4><<<dim3(GX, nAct), T, 0, stream>>>(P);
        }
        // gates (rh bf16 + z fp32)
        {
            NPs P{};
            for (int i = 0; i < nAct; ++i) {
                int n = nLo + i;
                P.n[i].A0 = bu + (long)n * PSZ; P.n[i].A1 = hBc[n]; P.n[i].Hb = hBc[n];
                P.n[i].Wp = WpG[n]; P.n[i].bias = bg[n];
                P.n[i].outB = rh + (long)n * RHSZ; P.n[i].outF = zb + (long)n * ZSZ;
            }
            mconv<32, 64, 128, 1, 3><<<dim3(GX, nAct), T, 0, stream>>>(P);
        }
        // cand + GRU update
        {
            NPs P{};
            for (int i = 0; i < nAct; ++i) {
                int n = nLo + i;
                P.n[i].A0 = bu + (long)n * PSZ; P.n[i].A1 = rh + (long)n * RHSZ;
                P.n[i].Zf = zb + (long)n * ZSZ; P.n[i].Hf = hFc[n];
                P.n[i].Wp = WpC[n]; P.n[i].bias = bc[n];
                P.n[i].outB = hBn[n]; P.n[i].outF = hFn[n];
            }
            mconv<32, 64, 64, 2, 3><<<dim3(GX, nAct), T, 0, stream>>>(P);
        }
        for (int n = nLo; n <= nHi; ++n) {
            float* tf = hFc[n]; hFc[n] = hFn[n]; hFn[n] = tf;
            bf16_t* tb = hBc[n]; hBc[n] = hBn[n]; hBn[n] = tb;
        }
    }

    hout_k<<<(8 * 64 * 64 * 64 + 255) / 256, 256, 0, stream>>>(hFc[2], (float*)d_out);
}